// Round 8
// baseline (189.904 us; speedup 1.0000x reference)
//
#include <hip/hip_runtime.h>
#include <cstdint>
#include <cstddef>

// MemoryEfficientAttention: B=2, S=2048, D=1024, H=16, Dh=64
// Pipeline: cvt_all -> gemm0 (QKV) -> attn v11 -> gemm1 (O-proj).
// R7 post-mortem: attn 45.3 (cvt_pk worked: VALU 51->47) but total flat ->
// the ~80 us of gemm0+gemm1 is the target. Both ran 2-barrier K-loops
// (stage fully serialized with compute; 16 iters x exposed load latency).
// R8: T3 "minimum 2-phase" conversion (m248v2: +10% at K=1024, our regime
// is MORE latency-exposed): double-buffered LDS, STAGE(kt+1) issued at TOP
// of iter, single raw s_barrier + vmcnt(0) at BOTTOM -> load latency hides
// under the iter's ds_read+MFMA. gemm0 LDS 64 KB -> 2 blocks/CU (prefetch
// replaces lost de-phase); gemm1 32 KB -> stays 4 blocks/CU (pure win).

typedef unsigned short u16;
typedef unsigned int u32;
typedef __bf16 bf16x8 __attribute__((ext_vector_type(8)));
typedef float f32x4 __attribute__((ext_vector_type(4)));

#define GLOAD_LDS16(gp, lp)                                                            \
  __builtin_amdgcn_global_load_lds((const __attribute__((address_space(1))) void*)(gp),\
                                   (__attribute__((address_space(3))) void*)(lp),      \
                                   16, 0, 0)

__device__ __forceinline__ u16 f2bf(float f) {  // round-to-nearest-even
  unsigned u = __builtin_bit_cast(unsigned, f);
  u = u + 0x7fffu + ((u >> 16) & 1u);
  return (u16)(u >> 16);
}

// two f32 -> packed bf16x2 (lo = a, hi = b), RNE, 1 instruction (gfx950)
__device__ __forceinline__ u32 cvtpk(float a, float b) {
  u32 r;
  asm("v_cvt_pk_bf16_f32 %0, %1, %2" : "=v"(r) : "v"(a), "v"(b));
  return r;
}

// scale folded into Q: attn uses exp2, so fold log2(e) too
#define QSCALE 0.1803368801111204f   // 0.125 * log2(e)

// ---------------------------------------------------------------------------
// Fused fp32 -> bf16 convert for x + 4 weight matrices (1 launch).
// ---------------------------------------------------------------------------
__global__ void cvt_all(const float* __restrict__ x,
                        const float* __restrict__ wq, const float* __restrict__ wk,
                        const float* __restrict__ wv, const float* __restrict__ wo,
                        u16* __restrict__ xb, u16* __restrict__ wqb,
                        u16* __restrict__ wkb, u16* __restrict__ wvb,
                        u16* __restrict__ wob) {
  int bx = blockIdx.x;
  const float* s; u16* d; int off;
  if (bx < 2048)      { s = x;  d = xb;  off = bx; }
  else if (bx < 2560) { s = wq; d = wqb; off = bx - 2048; }
  else if (bx < 3072) { s = wk; d = wkb; off = bx - 2560; }
  else if (bx < 3584) { s = wv; d = wvb; off = bx - 3072; }
  else                { s = wo; d = wob; off = bx - 3584; }
  int i = off * 2048 + threadIdx.x * 8;
  float4 a = *(const float4*)(s + i);
  float4 b = *(const float4*)(s + i + 4);
  uint4 o;
  o.x = f2bf(a.x) | ((u32)f2bf(a.y) << 16);
  o.y = f2bf(a.z) | ((u32)f2bf(a.w) << 16);
  o.z = f2bf(b.x) | ((u32)f2bf(b.y) << 16);
  o.w = f2bf(b.z) | ((u32)f2bf(b.w) << 16);
  *(uint4*)(d + i) = o;
}

// ---------------------------------------------------------------------------
// bf16 MFMA GEMM, T3 minimum-2-phase: C[m][n] = sum_k A[m][k]*W[n][k] + b[n]
// BM x BN tile, BK=64, 2-buf LDS, XOR-chunk swizzle, gload_lds(16B).
// Per iter: STAGE(kt+1 -> buf^1) issued FIRST; frag ds_reads + MFMA on
// buf; then vmcnt(0) + raw s_barrier (single barrier per iter; the stage
// latency hides under this iter's compute).
// XCD-swizzled block remap (bijective, TOT%8==0).
// MODE 0 (128x128, grid 24x32, LDS 64 KB, 2 blocks/CU): fused QKV:
//   Q TRANSPOSED+scaled [B,H,Dh,S]; K [B,H,S,Dh]; V TRANSPOSED [B,H,Dh,S].
// MODE 1 (64x64, grid 16x64, LDS 32 KB, 4 blocks/CU): O-proj, fp32 out.
// ---------------------------------------------------------------------------
template <int MODE, int BM, int BN>
__global__ __launch_bounds__(256, MODE == 0 ? 2 : 4) void gemm_mfma(
    const u16* __restrict__ A,
    const u16* __restrict__ W0, const u16* __restrict__ W1, const u16* __restrict__ W2,
    const float* __restrict__ b0, const float* __restrict__ b1, const float* __restrict__ b2,
    u16* __restrict__ o0, u16* __restrict__ o1, u16* __restrict__ o2,
    float* __restrict__ oF)
{
  constexpr int MF = BM / 32;     // m-frags per wave (wave owns BM/2 rows)
  constexpr int NF = BN / 32;     // n-frags per wave (wave owns BN/2 cols)
  constexpr int AG = BM / 32;     // A-staging glds per wave
  constexpr int BG = BN / 32;     // B-staging glds per wave
  constexpr int NY = (MODE == 0) ? 32 : 64;   // m-blocks
  constexpr int TOT = (MODE == 0) ? 24 * 32 : 16 * 64;
  constexpr int NT = 16;          // K-tiles (K=1024, BK=64)

  __shared__ __align__(16) u16 As[2][BM * 64];
  __shared__ __align__(16) u16 Bs[2][BN * 64];

  const int tid = threadIdx.x;
  const int w = tid >> 6, l = tid & 63;
  const int lane = l & 15, quad = l >> 4;
  const int wm = w >> 1, wn = w & 1;

  // XCD-aware bijective remap
  const int idb = blockIdx.y * gridDim.x + blockIdx.x;
  const int lid = (idb & 7) * (TOT >> 3) + (idb >> 3);
  const int m0 = (lid % NY) * BM;
  const int n0g = (lid / NY) * BN;

  const int src = (MODE == 0) ? (n0g >> 10) : 0;
  const u16* Wsel = (MODE == 0) ? (src == 0 ? W0 : (src == 1 ? W1 : W2)) : W0;
  const float* bsel = (MODE == 0) ? (src == 0 ? b0 : (src == 1 ? b1 : b2)) : b0;
  const int n_base = (MODE == 0) ? (n0g & 1023) : n0g;

  const int c8 = ((l & 7) ^ (l >> 3)) * 8;
  const int lrow = l >> 3;

  const u16* Ag0 = A + (size_t)m0 * 1024;
  const u16* Bg0 = Wsel + (size_t)n_base * 1024;

  // stage K-tile kt into buffer buf
  auto stage = [&](int buf, int kt) {
    const u16* Ag = Ag0 + kt * 64;
    const u16* Bg = Bg0 + kt * 64;
    #pragma unroll
    for (int i = 0; i < AG; ++i) {
      int rr = w * (8 * AG) + i * 8;
      GLOAD_LDS16(Ag + (size_t)(rr + lrow) * 1024 + c8, As[buf] + rr * 64);
    }
    #pragma unroll
    for (int i = 0; i < BG; ++i) {
      int rr = w * (8 * BG) + i * 8;
      GLOAD_LDS16(Bg + (size_t)(rr + lrow) * 1024 + c8, Bs[buf] + rr * 64);
    }
  };

  f32x4 acc[MF][NF] = {};

  // prologue: tile 0 -> buf 0, full drain
  stage(0, 0);
  asm volatile("s_waitcnt vmcnt(0)" ::: "memory");
  __builtin_amdgcn_s_barrier();
  asm volatile("" ::: "memory");

  for (int kt = 0; kt < NT; ++kt) {
    const int cur = kt & 1;
    // issue next tile's loads FIRST (latency hides under compute below);
    // dest buf cur^1 was last read at iter kt-1 (barrier below covered it)
    if (kt < NT - 1) stage(cur ^ 1, kt + 1);

    bf16x8 af[MF][2], bf[NF][2];
    #pragma unroll
    for (int mf = 0; mf < MF; ++mf)
      #pragma unroll
      for (int ks = 0; ks < 2; ++ks)
        af[mf][ks] = *(const bf16x8*)((const char*)As[cur] +
            (wm * (BM / 2) + mf * 16 + lane) * 128 + (((ks * 4 + quad) ^ (lane & 7)) * 16));
    #pragma unroll
    for (int nf = 0; nf < NF; ++nf)
      #pragma unroll
      for (int ks = 0; ks < 2; ++ks)
        bf[nf][ks] = *(const bf16x8*)((const char*)Bs[cur] +
            (wn * (BN / 2) + nf * 16 + lane) * 128 + (((ks * 4 + quad) ^ (lane & 7)) * 16));
    #pragma unroll
    for (int ks = 0; ks < 2; ++ks)
      #pragma unroll
      for (int mf = 0; mf < MF; ++mf)
        #pragma unroll
        for (int nf = 0; nf < NF; ++nf)
          acc[mf][nf] = __builtin_amdgcn_mfma_f32_16x16x32_bf16(
              af[mf][ks], bf[nf][ks], acc[mf][nf], 0, 0, 0);

    if (kt < NT - 1) {
      // own stage(kt+1) done; barrier covers all waves -> buf^1 ready
      asm volatile("s_waitcnt vmcnt(0)" ::: "memory");
      __builtin_amdgcn_s_barrier();
      asm volatile("" ::: "memory");
    }
  }

  float bb[NF];
  #pragma unroll
  for (int nf = 0; nf < NF; ++nf)
    bb[nf] = bsel[n_base + wn * (BN / 2) + nf * 16 + lane];

  u16* osel = (MODE == 0) ? (src == 0 ? o0 : (src == 1 ? o1 : o2)) : o0;

  #pragma unroll
  for (int mf = 0; mf < MF; ++mf) {
    int mb = m0 + wm * (BM / 2) + mf * 16 + quad * 4;
    #pragma unroll
    for (int nf = 0; nf < NF; ++nf) {
      int n_l = wn * (BN / 2) + nf * 16 + lane;
      if (MODE == 0 && src != 1) {
        // Q (scaled) and V: transposed [B,H,Dh,S], packed uint2 stores
        float sc = (src == 0) ? QSCALE : 1.0f;
        float v0 = (acc[mf][nf][0] + bb[nf]) * sc;
        float v1 = (acc[mf][nf][1] + bb[nf]) * sc;
        float v2 = (acc[mf][nf][2] + bb[nf]) * sc;
        float v3 = (acc[mf][nf][3] + bb[nf]) * sc;
        int bi = mb >> 11, s = mb & 2047;
        int n_in = n_base + n_l;
        int h = n_in >> 6, dh = n_in & 63;
        uint2 pk = make_uint2(cvtpk(v0, v1), cvtpk(v2, v3));
        *(uint2*)(osel + (((size_t)(bi * 16 + h) * 64 + dh) * 2048 + s)) = pk;
      } else {
        #pragma unroll
        for (int r = 0; r < 4; ++r) {
          float v = acc[mf][nf][r] + bb[nf];
          int m = mb + r;
          if (MODE == 0) {
            // K: [B,H,S,Dh], scalar stores
            int bi = m >> 11, s = m & 2047;
            int n_in = n_base + n_l;
            int h = n_in >> 6, dh = n_in & 63;
            osel[(((size_t)(bi * 16 + h) * 2048 + s) << 6) + dh] = f2bf(v);
          } else {
            oF[(size_t)m * 1024 + n0g + n_l] = v;
          }
        }
      }
    }
  }
}

// ---------------------------------------------------------------------------
// Flash attention v11 + XCD swizzle: 512 threads = 8 waves = 4 PAIRS.
// Pair g owns q rows g*32..+31; wave kh handles keys kh*32..+31 of each
// tile. Per wave-tile: ak 4 + bv 4 = 8 ds_read_b128; P in registers
// (cvt_pk + double permlane swap). Q gathered from Q^T once per block.
// Pipeline: K/V triple-buffered, raw s_barrier + s_waitcnt vmcnt(2),
// prefetch 2 tiles ahead. LDS = 48 KB -> 2 blocks/CU.
// ---------------------------------------------------------------------------
union SMemU {
  struct {
    u16 K[3][64 * 64];   // [key][dh]
    u16 V[3][64 * 64];   // [dh][key]
  } m;
  struct {
    float O[4][32 * 64]; // per-pair partial O [q][d]
    float L[4][32];      // per-pair partial lsum
  } f;
};

__global__ __launch_bounds__(512, 4) void attn_mfma(
    const u16* __restrict__ Qg_, const u16* __restrict__ Kg_,
    const u16* __restrict__ VTg_, u16* __restrict__ Og)
{
  __shared__ __align__(16) SMemU sm;

  const int tid = threadIdx.x;
  const int w = tid >> 6, l = tid & 63;
  const int lane = l & 15, quad = l >> 4;
  const int g = w >> 1;       // pair index: q rows g*32..+31
  const int kh = w & 1;       // key half: keys kh*32..+31 of each tile

  // XCD-aware bijective remap: 64 block-ids per XCD = 4 heads x 16 q-blocks
  const int idb = blockIdx.y * 16 + blockIdx.x;
  const int lid = (idb & 7) * 64 + (idb >> 3);
  const int bh = lid >> 4;          // b*16 + h
  const int q0 = (lid & 15) * 128;

  const u16* QTg = Qg_ + (size_t)bh * 64 * 2048;    // [dh][s]
  const u16* Kg  = Kg_ + (size_t)bh * 2048 * 64;    // [s][dh]
  const u16* VTg = VTg_ + (size_t)bh * 64 * 2048;   // [dh][s]

  const int c8 = ((l & 7) ^ (l >> 3)) * 8;   // staging chunk swizzle
  const int lrow = l >> 3;
  const int rr = w * 8;       // this wave's 8 staging rows (1 glds per tensor)

  // Q B-frags gathered from Q^T (once per block; 32 scalar loads)
  const int qcol = q0 + g * 32 + lane;
  bf16x8 bq[2][2];
  #pragma unroll
  for (int qf = 0; qf < 2; ++qf)
    #pragma unroll
    for (int ks = 0; ks < 2; ++ks) {
      bf16x8 v;
      #pragma unroll
      for (int j = 0; j < 8; ++j)
        v[j] = __builtin_bit_cast(__bf16,
            QTg[(size_t)(ks * 32 + quad * 8 + j) * 2048 + qcol + qf * 16]);
      bq[qf][ks] = v;
    }

  // stage tile 0 -> buf 0, tile 1 -> buf 1 (4 glds in flight per wave)
  GLOAD_LDS16(Kg + (size_t)(rr + lrow) * 64 + c8, sm.m.K[0] + rr * 64);
  GLOAD_LDS16(VTg + (size_t)(rr + lrow) * 2048 + c8, sm.m.V[0] + rr * 64);
  GLOAD_LDS16(Kg + (size_t)(64 + rr + lrow) * 64 + c8, sm.m.K[1] + rr * 64);
  GLOAD_LDS16(VTg + (size_t)(rr + lrow) * 2048 + 64 + c8, sm.m.V[1] + rr * 64);

  f32x4 oa[2][4] = {};
  float lsum[2] = {0.f, 0.f};
  int cur = 0;

  for (int kt = 0; kt < 32; ++kt) {
    // tile kt staged when OUR 2 oldest glds (tile kt) are done AND every
    // other wave's are too (barrier). Tile kt+1's 2 glds stay in flight.
    if (kt < 31) asm volatile("s_waitcnt vmcnt(2)" ::: "memory");
    else         asm volatile("s_waitcnt vmcnt(0)" ::: "memory");
    __builtin_amdgcn_s_barrier();
    asm volatile("" ::: "memory");

    // prefetch tile kt+2 into the buffer all waves finished at iter kt-1
    if (kt < 30) {
      int pf = (cur == 0) ? 2 : cur - 1;   // (cur+2)%3
      GLOAD_LDS16(Kg + (size_t)((kt + 2) * 64 + rr + lrow) * 64 + c8,
                  sm.m.K[pf] + rr * 64);
      GLOAD_LDS16(VTg + (size_t)(rr + lrow) * 2048 + (kt + 2) * 64 + c8,
                  sm.m.V[pf] + rr * 64);
    }

    // S^T = K·Q^T over this wave's 32 keys:
    // sa[kf][qf]: key = kh*32 + kf*16 + quad*4 + r, q = qf*16 + lane
    f32x4 sa[2][2] = {};
    #pragma unroll
    for (int ks = 0; ks < 2; ++ks) {
      bf16x8 ak[2];
      #pragma unroll
      for (int kf = 0; kf < 2; ++kf)
        ak[kf] = *(const bf16x8*)((const char*)sm.m.K[cur] +
            (kh * 32 + kf * 16 + lane) * 128 + (((ks * 4 + quad) ^ (lane & 7)) * 16));
      #pragma unroll
      for (int kf = 0; kf < 2; ++kf)
        #pragma unroll
        for (int qf = 0; qf < 2; ++qf)
          sa[kf][qf] = __builtin_amdgcn_mfma_f32_16x16x32_bf16(
              ak[kf], bq[qf][ks], sa[kf][qf], 0, 0, 0);
    }

    // softmax numerator (bare exp2) + in-register P relayout:
    // X pair (kf=0) / Y pair (kf=1) -> cvt_pk -> double permlane swap ->
    // PV A-frags (T12).
    bf16x8 ap[2];
    #pragma unroll
    for (int qf = 0; qf < 2; ++qf) {
      float x0 = __builtin_amdgcn_exp2f(sa[0][qf][0]);
      float x1 = __builtin_amdgcn_exp2f(sa[0][qf][1]);
      float x2 = __builtin_amdgcn_exp2f(sa[0][qf][2]);
      float x3 = __builtin_amdgcn_exp2f(sa[0][qf][3]);
      float y0 = __builtin_amdgcn_exp2f(sa[1][qf][0]);
      float y1 = __builtin_amdgcn_exp2f(sa[1][qf][1]);
      float y2 = __builtin_amdgcn_exp2f(sa[1][qf][2]);
      float y3 = __builtin_amdgcn_exp2f(sa[1][qf][3]);
      lsum[qf] += ((x0 + x1) + (x2 + x3)) + ((y0 + y1) + (y2 + y3));
      u32 X0 = cvtpk(x0, x1), X1 = cvtpk(x2, x3);
      u32 Y0 = cvtpk(y0, y1), Y1 = cvtpk(y2, y3);
      asm("v_permlane32_swap_b32 %0, %1" : "+v"(X0), "+v"(Y0));
      asm("v_permlane16_swap_b32 %0, %1" : "+v"(X0), "+v"(Y0));
      asm("v_permlane32_swap_b32 %0, %1" : "+v"(X1), "+v"(Y1));
      asm("v_permlane16_swap_b32 %0, %1" : "+v"(X1), "+v"(Y1));
      uint4 d4 = make_uint4(X0, X1, Y0, Y1);  // A-frag dwords 0..3
      ap[qf] = __builtin_bit_cast(bf16x8, d4);
    }

    // O += P·V over this wave's 32 keys (single mfma16 K-depth):
    {
      bf16x8 bv[4];
      #pragma unroll
      for (int df = 0; df < 4; ++df)
        bv[df] = *(const bf16x8*)((const char*)sm.m.V[cur] +
            (df * 16 + lane) * 128 + (((kh * 4 + quad) ^ (lane & 7)) * 16));
      #pragma unroll
      for (int qf = 0; qf < 2; ++qf)
        #pragma unroll
        for (int df = 0; df < 4; ++df)
          oa[qf][df] = __builtin_amdgcn_mfma_f32_16x16x32_bf16(
              ap[qf], bv[df], oa[qf][df], 0, 0, 0);
    }

    cur = (cur == 2) ? 0 : cur + 1;
  }

  // reduce lsum across quads
  #pragma unroll
  for (int qf = 0; qf < 2; ++qf) {
    lsum[qf] += __shfl_xor(lsum[qf], 16);
    lsum[qf] += __shfl_xor(lsum[qf], 32);
  }

  // ---- pair combine: kh=1 wave publishes partials, kh=0 wave merges ----
  __syncthreads();  // main-loop LDS reads complete; safe to alias via union
  if (kh == 1) {
    #pragma unroll
    for (int qf = 0; qf < 2; ++qf)
      #pragma unroll
      for (int df = 0; df < 4; ++df)
        #pragma unroll
        for (int r = 0; r < 4; ++r)
          sm.f.O[g][(qf * 16 + quad * 4 + r) * 64 + df * 16 + lane] = oa[qf][df][r];
    if (l < 16) {
      sm.f.L[g][l] = lsum[0];
      sm.f.L[g][16 + l] = lsum[1];
    }
  }
  __syncthreads();
  if (kh == 0) {
    const int b = bh >> 4, hh = bh & 15;
    u16* Ob = Og + ((size_t)b * 2048 + q0 + g * 32) * 1024 + hh * 64;
    float ltot[2];
    #pragma unroll
    for (int qf = 0; qf < 2; ++qf)
      ltot[qf] = lsum[qf] + sm.f.L[g][qf * 16 + lane];
    #pragma unroll
    for (int qf = 0; qf < 2; ++qf)
      #pragma unroll
      for (int r = 0; r < 4; ++r) {
        float inv = 1.0f / __shfl(ltot[qf], quad * 4 + r, 16);
        int qrow = qf * 16 + quad * 4 + r;
        #pragma unroll
        for (int df = 0; df < 4; ++df) {
          float v = oa[qf][df][r] + sm.f.O[g][qrow * 64 + df * 16 + lane];
          Ob[(size_t)qrow * 1024 + df * 16 + lane] = f2bf(v * inv);
        }
      }
  }
}

// ---------------------------------------------------------------------------
// Workspace (u16): xb[4M] wq[1M] wk[1M] wv[1M] wo[1M] Q[4M] K[4M] VT[4M]
// AO[4M] = 24M u16 = 48 MB.
// ---------------------------------------------------------------------------
extern "C" void kernel_launch(void* const* d_in, const int* in_sizes, int n_in,
                              void* d_out, int out_size, void* d_ws, size_t ws_size,
                              hipStream_t stream)
{
  (void)in_sizes; (void)n_in; (void)out_size; (void)ws_size;
  const float* x  = (const float*)d_in[0];
  const float* Wq = (const float*)d_in[1];
  const float* bq = (const float*)d_in[2];
  const float* Wk = (const float*)d_in[3];
  const float* bk = (const float*)d_in[4];
  const float* Wv = (const float*)d_in[5];
  const float* bv = (const float*)d_in[6];
  const float* Wo = (const float*)d_in[7];
  const float* bo = (const float*)d_in[8];
  float* y = (float*)d_out;

  const size_t NM = (size_t)4096 * 1024;
  u16* xb  = (u16*)d_ws;
  u16* wqb = xb + NM;
  u16* wkb = wqb + 1024 * 1024;
  u16* wvb = wkb + 1024 * 1024;
  u16* wob = wvb + 1024 * 1024;
  u16* Qb  = wob + 1024 * 1024;   // Q^T [B,H,Dh,S]
  u16* Kb  = Qb + NM;             // K   [B,H,S,Dh]
  u16* VTb = Kb + NM;             // V^T [B,H,Dh,S]
  u16* AOb = VTb + NM;

  cvt_all<<<4096, 256, 0, stream>>>(x, Wq, Wk, Wv, Wo, xb, wqb, wkb, wvb, wob);

  gemm_mfma<0, 128, 128><<<dim3(24, 32), 256, 0, stream>>>(
      xb, wqb, wkb, wvb, bq, bk, bv, Qb, Kb, VTb, nullptr);

  attn_mfma<<<dim3(16, 32), 512, 0, stream>>>(Qb, Kb, VTb, AOb);

  gemm_mfma<1, 64, 64><<<dim3(16, 64), 256, 0, stream>>>(
      AOb, wob, nullptr, nullptr, bo, nullptr, nullptr,
      nullptr, nullptr, nullptr, y);
}

// Round 9
// 171.674 us; speedup vs baseline: 1.1062x; 1.1062x over previous
//
#include <hip/hip_runtime.h>
#include <cstdint>
#include <cstddef>

// MemoryEfficientAttention: B=2, S=2048, D=1024, H=16, Dh=64
// Pipeline: cvt_all -> gemm0 (QKV) -> attn v11 -> gemm1 (O-proj).
// R8 post-mortem: 2-phase GEMM conversion REGRESSED both GEMMs (gemm0
// 44->49.4: vmcnt(0)-drain/iter at 2 blk/CU < 1-buf at 3 blk/CU).
// Reverted to R7 single-buffer loops. R8 counters exposed the real lever:
// gemm0 FETCH 68.7 MB (= full xb re-fetched per XCD; 1D swizzle gave each
// XCD all 32 m-panels). This round: 2D XCD chunking -- each XCD owns an
// 8m x 12n rectangle (5.2 MB working set ~= L2) for gemm0, 16m x 8n
// (3.1 MB) for gemm1 -> staging loads become L2 hits (~200 cyc vs ~900);
// gemm0 is latency-bound so this attacks its stall directly.
// attn: + T5 setprio(1) around MFMA clusters (m191: +4-7% on attn).

typedef unsigned short u16;
typedef unsigned int u32;
typedef __bf16 bf16x8 __attribute__((ext_vector_type(8)));
typedef float f32x4 __attribute__((ext_vector_type(4)));

#define GLOAD_LDS16(gp, lp)                                                            \
  __builtin_amdgcn_global_load_lds((const __attribute__((address_space(1))) void*)(gp),\
                                   (__attribute__((address_space(3))) void*)(lp),      \
                                   16, 0, 0)

__device__ __forceinline__ u16 f2bf(float f) {  // round-to-nearest-even
  unsigned u = __builtin_bit_cast(unsigned, f);
  u = u + 0x7fffu + ((u >> 16) & 1u);
  return (u16)(u >> 16);
}

// two f32 -> packed bf16x2 (lo = a, hi = b), RNE, 1 instruction (gfx950)
__device__ __forceinline__ u32 cvtpk(float a, float b) {
  u32 r;
  asm("v_cvt_pk_bf16_f32 %0, %1, %2" : "=v"(r) : "v"(a), "v"(b));
  return r;
}

// scale folded into Q: attn uses exp2, so fold log2(e) too
#define QSCALE 0.1803368801111204f   // 0.125 * log2(e)

// ---------------------------------------------------------------------------
// Fused fp32 -> bf16 convert for x + 4 weight matrices (1 launch).
// ---------------------------------------------------------------------------
__global__ void cvt_all(const float* __restrict__ x,
                        const float* __restrict__ wq, const float* __restrict__ wk,
                        const float* __restrict__ wv, const float* __restrict__ wo,
                        u16* __restrict__ xb, u16* __restrict__ wqb,
                        u16* __restrict__ wkb, u16* __restrict__ wvb,
                        u16* __restrict__ wob) {
  int bx = blockIdx.x;
  const float* s; u16* d; int off;
  if (bx < 2048)      { s = x;  d = xb;  off = bx; }
  else if (bx < 2560) { s = wq; d = wqb; off = bx - 2048; }
  else if (bx < 3072) { s = wk; d = wkb; off = bx - 2560; }
  else if (bx < 3584) { s = wv; d = wvb; off = bx - 3072; }
  else                { s = wo; d = wob; off = bx - 3584; }
  int i = off * 2048 + threadIdx.x * 8;
  float4 a = *(const float4*)(s + i);
  float4 b = *(const float4*)(s + i + 4);
  uint4 o;
  o.x = f2bf(a.x) | ((u32)f2bf(a.y) << 16);
  o.y = f2bf(a.z) | ((u32)f2bf(a.w) << 16);
  o.z = f2bf(b.x) | ((u32)f2bf(b.y) << 16);
  o.w = f2bf(b.z) | ((u32)f2bf(b.w) << 16);
  *(uint4*)(d + i) = o;
}

// ---------------------------------------------------------------------------
// bf16 MFMA GEMM (R7 single-buffer structure): C[m][n] = sum_k A[m][k]*W[n][k]+b[n]
// BM x BN tile, BK=64, XOR-chunk-swizzled LDS via global_load_lds(16B).
// 2D XCD chunking: XCD (idb&7) -> rectangle of the (m,n) tile grid so each
// XCD's working set ~= L2 (gemm0: 8m x 12n = 5.2 MB; gemm1: 16m x 8n = 3.1 MB).
// MODE 0 (128x128, grid 24x32 = 768 = 3 blocks/CU): fused QKV (N=3072):
//   Q TRANSPOSED+scaled [B,H,Dh,S]; K [B,H,S,Dh]; V TRANSPOSED [B,H,Dh,S].
// MODE 1 (64x64, grid 16x64 = 1024 = 4 blocks/CU): O-proj, fp32 flat out.
// ---------------------------------------------------------------------------
template <int MODE, int BM, int BN>
__global__ __launch_bounds__(256, MODE == 0 ? 3 : 4) void gemm_mfma(
    const u16* __restrict__ A,
    const u16* __restrict__ W0, const u16* __restrict__ W1, const u16* __restrict__ W2,
    const float* __restrict__ b0, const float* __restrict__ b1, const float* __restrict__ b2,
    u16* __restrict__ o0, u16* __restrict__ o1, u16* __restrict__ o2,
    float* __restrict__ oF)
{
  constexpr int MF = BM / 32;     // m-frags per wave (wave owns BM/2 rows)
  constexpr int NF = BN / 32;     // n-frags per wave (wave owns BN/2 cols)
  constexpr int AG = BM / 32;     // A-staging glds per wave
  constexpr int BG = BN / 32;     // B-staging glds per wave

  __shared__ __align__(16) u16 As[BM * 64];
  __shared__ __align__(16) u16 Bs[BN * 64];

  const int tid = threadIdx.x;
  const int w = tid >> 6, l = tid & 63;
  const int lane = l & 15, quad = l >> 4;
  const int wm = w >> 1, wn = w & 1;

  // 2D XCD chunking: xcd = idb&7 -> (xr, xc) = (xcd>>1, xcd&1); j walks the
  // XCD's rectangle m-fastest. Bijective; blocks on one XCD share panels.
  const int idb = blockIdx.y * gridDim.x + blockIdx.x;
  const int xcd = idb & 7, j = idb >> 3;
  int m_idx, n_idx;
  if (MODE == 0) {          // 32m x 24n -> per XCD 8m x 12n
    m_idx = (xcd >> 1) * 8 + (j & 7);
    n_idx = (xcd & 1) * 12 + (j >> 3);
  } else {                  // 64m x 16n -> per XCD 16m x 8n
    m_idx = (xcd >> 1) * 16 + (j & 15);
    n_idx = (xcd & 1) * 8 + (j >> 4);
  }
  const int m0 = m_idx * BM;
  const int n0g = n_idx * BN;

  const int src = (MODE == 0) ? (n0g >> 10) : 0;
  const u16* Wsel = (MODE == 0) ? (src == 0 ? W0 : (src == 1 ? W1 : W2)) : W0;
  const float* bsel = (MODE == 0) ? (src == 0 ? b0 : (src == 1 ? b1 : b2)) : b0;
  const int n_base = (MODE == 0) ? (n0g & 1023) : n0g;

  const int c8 = ((l & 7) ^ (l >> 3)) * 8;
  const int lrow = l >> 3;

  f32x4 acc[MF][NF] = {};

  for (int kt = 0; kt < 1024; kt += 64) {
    __syncthreads();
    const u16* Ag = A + (size_t)m0 * 1024 + kt;
    const u16* Bg = Wsel + (size_t)n_base * 1024 + kt;
    #pragma unroll
    for (int i = 0; i < AG; ++i) {
      int rr = w * (8 * AG) + i * 8;
      GLOAD_LDS16(Ag + (size_t)(rr + lrow) * 1024 + c8, As + rr * 64);
    }
    #pragma unroll
    for (int i = 0; i < BG; ++i) {
      int rr = w * (8 * BG) + i * 8;
      GLOAD_LDS16(Bg + (size_t)(rr + lrow) * 1024 + c8, Bs + rr * 64);
    }
    __syncthreads();

    bf16x8 af[MF][2], bf[NF][2];
    #pragma unroll
    for (int mf = 0; mf < MF; ++mf)
      #pragma unroll
      for (int ks = 0; ks < 2; ++ks)
        af[mf][ks] = *(const bf16x8*)((const char*)As +
            (wm * (BM / 2) + mf * 16 + lane) * 128 + (((ks * 4 + quad) ^ (lane & 7)) * 16));
    #pragma unroll
    for (int nf = 0; nf < NF; ++nf)
      #pragma unroll
      for (int ks = 0; ks < 2; ++ks)
        bf[nf][ks] = *(const bf16x8*)((const char*)Bs +
            (wn * (BN / 2) + nf * 16 + lane) * 128 + (((ks * 4 + quad) ^ (lane & 7)) * 16));
    #pragma unroll
    for (int ks = 0; ks < 2; ++ks)
      #pragma unroll
      for (int mf = 0; mf < MF; ++mf)
        #pragma unroll
        for (int nf = 0; nf < NF; ++nf)
          acc[mf][nf] = __builtin_amdgcn_mfma_f32_16x16x32_bf16(
              af[mf][ks], bf[nf][ks], acc[mf][nf], 0, 0, 0);
  }

  float bb[NF];
  #pragma unroll
  for (int nf = 0; nf < NF; ++nf)
    bb[nf] = bsel[n_base + wn * (BN / 2) + nf * 16 + lane];

  u16* osel = (MODE == 0) ? (src == 0 ? o0 : (src == 1 ? o1 : o2)) : o0;

  #pragma unroll
  for (int mf = 0; mf < MF; ++mf) {
    int mb = m0 + wm * (BM / 2) + mf * 16 + quad * 4;
    #pragma unroll
    for (int nf = 0; nf < NF; ++nf) {
      int n_l = wn * (BN / 2) + nf * 16 + lane;
      if (MODE == 0 && src != 1) {
        // Q (scaled) and V: transposed [B,H,Dh,S], packed uint2 stores
        float sc = (src == 0) ? QSCALE : 1.0f;
        float v0 = (acc[mf][nf][0] + bb[nf]) * sc;
        float v1 = (acc[mf][nf][1] + bb[nf]) * sc;
        float v2 = (acc[mf][nf][2] + bb[nf]) * sc;
        float v3 = (acc[mf][nf][3] + bb[nf]) * sc;
        int bi = mb >> 11, s = mb & 2047;
        int n_in = n_base + n_l;
        int h = n_in >> 6, dh = n_in & 63;
        uint2 pk = make_uint2(cvtpk(v0, v1), cvtpk(v2, v3));
        *(uint2*)(osel + (((size_t)(bi * 16 + h) * 64 + dh) * 2048 + s)) = pk;
      } else {
        #pragma unroll
        for (int r = 0; r < 4; ++r) {
          float v = acc[mf][nf][r] + bb[nf];
          int m = mb + r;
          if (MODE == 0) {
            // K: [B,H,S,Dh], scalar stores
            int bi = m >> 11, s = m & 2047;
            int n_in = n_base + n_l;
            int h = n_in >> 6, dh = n_in & 63;
            osel[(((size_t)(bi * 16 + h) * 2048 + s) << 6) + dh] = f2bf(v);
          } else {
            oF[(size_t)m * 1024 + n0g + n_l] = v;
          }
        }
      }
    }
  }
}

// ---------------------------------------------------------------------------
// Flash attention v11 + XCD swizzle + T5 setprio: 512 threads = 8 waves =
// 4 PAIRS. Pair g owns q rows g*32..+31; wave kh handles keys kh*32..+31
// of each tile. Per wave-tile: ak 4 + bv 4 = 8 ds_read_b128; P in
// registers (cvt_pk + double permlane swap). Q gathered from Q^T once.
// Pipeline: K/V triple-buffered, raw s_barrier + s_waitcnt vmcnt(2),
// prefetch 2 tiles ahead. LDS = 48 KB -> 2 blocks/CU.
// ---------------------------------------------------------------------------
union SMemU {
  struct {
    u16 K[3][64 * 64];   // [key][dh]
    u16 V[3][64 * 64];   // [dh][key]
  } m;
  struct {
    float O[4][32 * 64]; // per-pair partial O [q][d]
    float L[4][32];      // per-pair partial lsum
  } f;
};

__global__ __launch_bounds__(512, 4) void attn_mfma(
    const u16* __restrict__ Qg_, const u16* __restrict__ Kg_,
    const u16* __restrict__ VTg_, u16* __restrict__ Og)
{
  __shared__ __align__(16) SMemU sm;

  const int tid = threadIdx.x;
  const int w = tid >> 6, l = tid & 63;
  const int lane = l & 15, quad = l >> 4;
  const int g = w >> 1;       // pair index: q rows g*32..+31
  const int kh = w & 1;       // key half: keys kh*32..+31 of each tile

  // XCD-aware bijective remap: 64 block-ids per XCD = 4 heads x 16 q-blocks
  const int idb = blockIdx.y * 16 + blockIdx.x;
  const int lid = (idb & 7) * 64 + (idb >> 3);
  const int bh = lid >> 4;          // b*16 + h
  const int q0 = (lid & 15) * 128;

  const u16* QTg = Qg_ + (size_t)bh * 64 * 2048;    // [dh][s]
  const u16* Kg  = Kg_ + (size_t)bh * 2048 * 64;    // [s][dh]
  const u16* VTg = VTg_ + (size_t)bh * 64 * 2048;   // [dh][s]

  const int c8 = ((l & 7) ^ (l >> 3)) * 8;   // staging chunk swizzle
  const int lrow = l >> 3;
  const int rr = w * 8;       // this wave's 8 staging rows (1 glds per tensor)

  // Q B-frags gathered from Q^T (once per block; 32 scalar loads)
  const int qcol = q0 + g * 32 + lane;
  bf16x8 bq[2][2];
  #pragma unroll
  for (int qf = 0; qf < 2; ++qf)
    #pragma unroll
    for (int ks = 0; ks < 2; ++ks) {
      bf16x8 v;
      #pragma unroll
      for (int j = 0; j < 8; ++j)
        v[j] = __builtin_bit_cast(__bf16,
            QTg[(size_t)(ks * 32 + quad * 8 + j) * 2048 + qcol + qf * 16]);
      bq[qf][ks] = v;
    }

  // stage tile 0 -> buf 0, tile 1 -> buf 1 (4 glds in flight per wave)
  GLOAD_LDS16(Kg + (size_t)(rr + lrow) * 64 + c8, sm.m.K[0] + rr * 64);
  GLOAD_LDS16(VTg + (size_t)(rr + lrow) * 2048 + c8, sm.m.V[0] + rr * 64);
  GLOAD_LDS16(Kg + (size_t)(64 + rr + lrow) * 64 + c8, sm.m.K[1] + rr * 64);
  GLOAD_LDS16(VTg + (size_t)(rr + lrow) * 2048 + 64 + c8, sm.m.V[1] + rr * 64);

  f32x4 oa[2][4] = {};
  float lsum[2] = {0.f, 0.f};
  int cur = 0;

  for (int kt = 0; kt < 32; ++kt) {
    // tile kt staged when OUR 2 oldest glds (tile kt) are done AND every
    // other wave's are too (barrier). Tile kt+1's 2 glds stay in flight.
    if (kt < 31) asm volatile("s_waitcnt vmcnt(2)" ::: "memory");
    else         asm volatile("s_waitcnt vmcnt(0)" ::: "memory");
    __builtin_amdgcn_s_barrier();
    asm volatile("" ::: "memory");

    // prefetch tile kt+2 into the buffer all waves finished at iter kt-1
    if (kt < 30) {
      int pf = (cur == 0) ? 2 : cur - 1;   // (cur+2)%3
      GLOAD_LDS16(Kg + (size_t)((kt + 2) * 64 + rr + lrow) * 64 + c8,
                  sm.m.K[pf] + rr * 64);
      GLOAD_LDS16(VTg + (size_t)(rr + lrow) * 2048 + (kt + 2) * 64 + c8,
                  sm.m.V[pf] + rr * 64);
    }

    // S^T = K·Q^T over this wave's 32 keys:
    // sa[kf][qf]: key = kh*32 + kf*16 + quad*4 + r, q = qf*16 + lane
    f32x4 sa[2][2] = {};
    #pragma unroll
    for (int ks = 0; ks < 2; ++ks) {
      bf16x8 ak[2];
      #pragma unroll
      for (int kf = 0; kf < 2; ++kf)
        ak[kf] = *(const bf16x8*)((const char*)sm.m.K[cur] +
            (kh * 32 + kf * 16 + lane) * 128 + (((ks * 4 + quad) ^ (lane & 7)) * 16));
      __builtin_amdgcn_s_setprio(1);
      #pragma unroll
      for (int kf = 0; kf < 2; ++kf)
        #pragma unroll
        for (int qf = 0; qf < 2; ++qf)
          sa[kf][qf] = __builtin_amdgcn_mfma_f32_16x16x32_bf16(
              ak[kf], bq[qf][ks], sa[kf][qf], 0, 0, 0);
      __builtin_amdgcn_s_setprio(0);
    }

    // softmax numerator (bare exp2) + in-register P relayout:
    // X pair (kf=0) / Y pair (kf=1) -> cvt_pk -> double permlane swap ->
    // PV A-frags (T12).
    bf16x8 ap[2];
    #pragma unroll
    for (int qf = 0; qf < 2; ++qf) {
      float x0 = __builtin_amdgcn_exp2f(sa[0][qf][0]);
      float x1 = __builtin_amdgcn_exp2f(sa[0][qf][1]);
      float x2 = __builtin_amdgcn_exp2f(sa[0][qf][2]);
      float x3 = __builtin_amdgcn_exp2f(sa[0][qf][3]);
      float y0 = __builtin_amdgcn_exp2f(sa[1][qf][0]);
      float y1 = __builtin_amdgcn_exp2f(sa[1][qf][1]);
      float y2 = __builtin_amdgcn_exp2f(sa[1][qf][2]);
      float y3 = __builtin_amdgcn_exp2f(sa[1][qf][3]);
      lsum[qf] += ((x0 + x1) + (x2 + x3)) + ((y0 + y1) + (y2 + y3));
      u32 X0 = cvtpk(x0, x1), X1 = cvtpk(x2, x3);
      u32 Y0 = cvtpk(y0, y1), Y1 = cvtpk(y2, y3);
      asm("v_permlane32_swap_b32 %0, %1" : "+v"(X0), "+v"(Y0));
      asm("v_permlane16_swap_b32 %0, %1" : "+v"(X0), "+v"(Y0));
      asm("v_permlane32_swap_b32 %0, %1" : "+v"(X1), "+v"(Y1));
      asm("v_permlane16_swap_b32 %0, %1" : "+v"(X1), "+v"(Y1));
      uint4 d4 = make_uint4(X0, X1, Y0, Y1);  // A-frag dwords 0..3
      ap[qf] = __builtin_bit_cast(bf16x8, d4);
    }

    // O += P·V over this wave's 32 keys (single mfma16 K-depth):
    {
      bf16x8 bv[4];
      #pragma unroll
      for (int df = 0; df < 4; ++df)
        bv[df] = *(const bf16x8*)((const char*)sm.m.V[cur] +
            (df * 16 + lane) * 128 + (((kh * 4 + quad) ^ (lane & 7)) * 16));
      __builtin_amdgcn_s_setprio(1);
      #pragma unroll
      for (int qf = 0; qf < 2; ++qf)
        #pragma unroll
        for (int df = 0; df < 4; ++df)
          oa[qf][df] = __builtin_amdgcn_mfma_f32_16x16x32_bf16(
              ap[qf], bv[df], oa[qf][df], 0, 0, 0);
      __builtin_amdgcn_s_setprio(0);
    }

    cur = (cur == 2) ? 0 : cur + 1;
  }

  // reduce lsum across quads
  #pragma unroll
  for (int qf = 0; qf < 2; ++qf) {
    lsum[qf] += __shfl_xor(lsum[qf], 16);
    lsum[qf] += __shfl_xor(lsum[qf], 32);
  }

  // ---- pair combine: kh=1 wave publishes partials, kh=0 wave merges ----
  __syncthreads();  // main-loop LDS reads complete; safe to alias via union
  if (kh == 1) {
    #pragma unroll
    for (int qf = 0; qf < 2; ++qf)
      #pragma unroll
      for (int df = 0; df < 4; ++df)
        #pragma unroll
        for (int r = 0; r < 4; ++r)
          sm.f.O[g][(qf * 16 + quad * 4 + r) * 64 + df * 16 + lane] = oa[qf][df][r];
    if (l < 16) {
      sm.f.L[g][l] = lsum[0];
      sm.f.L[g][16 + l] = lsum[1];
    }
  }
  __syncthreads();
  if (kh == 0) {
    const int b = bh >> 4, hh = bh & 15;
    u16* Ob = Og + ((size_t)b * 2048 + q0 + g * 32) * 1024 + hh * 64;
    float ltot[2];
    #pragma unroll
    for (int qf = 0; qf < 2; ++qf)
      ltot[qf] = lsum[qf] + sm.f.L[g][qf * 16 + lane];
    #pragma unroll
    for (int qf = 0; qf < 2; ++qf)
      #pragma unroll
      for (int r = 0; r < 4; ++r) {
        float inv = 1.0f / __shfl(ltot[qf], quad * 4 + r, 16);
        int qrow = qf * 16 + quad * 4 + r;
        #pragma unroll
        for (int df = 0; df < 4; ++df) {
          float v = oa[qf][df][r] + sm.f.O[g][qrow * 64 + df * 16 + lane];
          Ob[(size_t)qrow * 1024 + df * 16 + lane] = f2bf(v * inv);
        }
      }
  }
}

// ---------------------------------------------------------------------------
// Workspace (u16): xb[4M] wq[1M] wk[1M] wv[1M] wo[1M] Q[4M] K[4M] VT[4M]
// AO[4M] = 24M u16 = 48 MB.
// ---------------------------------------------------------------------------
extern "C" void kernel_launch(void* const* d_in, const int* in_sizes, int n_in,
                              void* d_out, int out_size, void* d_ws, size_t ws_size,
                              hipStream_t stream)
{
  (void)in_sizes; (void)n_in; (void)out_size; (void)ws_size;
  const float* x  = (const float*)d_in[0];
  const float* Wq = (const float*)d_in[1];
  const float* bq = (const float*)d_in[2];
  const float* Wk = (const float*)d_in[3];
  const float* bk = (const float*)d_in[4];
  const float* Wv = (const float*)d_in[5];
  const float* bv = (const float*)d_in[6];
  const float* Wo = (const float*)d_in[7];
  const float* bo = (const float*)d_in[8];
  float* y = (float*)d_out;

  const size_t NM = (size_t)4096 * 1024;
  u16* xb  = (u16*)d_ws;
  u16* wqb = xb + NM;
  u16* wkb = wqb + 1024 * 1024;
  u16* wvb = wkb + 1024 * 1024;
  u16* wob = wvb + 1024 * 1024;
  u16* Qb  = wob + 1024 * 1024;   // Q^T [B,H,Dh,S]
  u16* Kb  = Qb + NM;             // K   [B,H,S,Dh]
  u16* VTb = Kb + NM;             // V^T [B,H,Dh,S]
  u16* AOb = VTb + NM;

  cvt_all<<<4096, 256, 0, stream>>>(x, Wq, Wk, Wv, Wo, xb, wqb, wkb, wvb, wob);

  gemm_mfma<0, 128, 128><<<dim3(24, 32), 256, 0, stream>>>(
      xb, wqb, wkb, wvb, bq, bk, bv, Qb, Kb, VTb, nullptr);

  attn_mfma<<<dim3(16, 32), 512, 0, stream>>>(Qb, Kb, VTb, AOb);

  gemm_mfma<1, 64, 64><<<dim3(16, 64), 256, 0, stream>>>(
      AOb, wob, nullptr, nullptr, bo, nullptr, nullptr,
      nullptr, nullptr, nullptr, y);
}